// Round 1
// baseline (327.404 us; speedup 1.0000x reference)
//
#include <hip/hip_runtime.h>

#define D_MODEL 1024
#define N_HEADS 16
#define D_KH    64
#define BATCH   4
#define SEQ     2048
#define M_TOTAL (BATCH*SEQ)   // 8192

typedef __attribute__((ext_vector_type(8))) short short8;
typedef __attribute__((ext_vector_type(4))) float f32x4;
typedef __attribute__((ext_vector_type(4))) unsigned short u16x4;

__device__ __forceinline__ unsigned short f2bf(float f) {
  union { float f; unsigned u; } v; v.f = f;
  unsigned r = v.u + 0x7FFFu + ((v.u >> 16) & 1u);
  return (unsigned short)(r >> 16);
}

// ---------------------------------------------------------------- cvt_q
// Q fp32 [8192,1024] -> bf16, coalesced float4 reads.
__global__ __launch_bounds__(256) void cvt_q(const float* __restrict__ Q,
                                             unsigned short* __restrict__ Qbf) {
  size_t i = (size_t)blockIdx.x * 256 + threadIdx.x;
  float4 v = ((const float4*)Q)[i];
  u16x4 o;
  o[0] = f2bf(v.x); o[1] = f2bf(v.y); o[2] = f2bf(v.z); o[3] = f2bf(v.w);
  ((u16x4*)Qbf)[i] = o;
}

// ---------------------------------------------------------------- cvt_wt
// W [k][n] fp32 -> WT [n][k] bf16, 32x32 LDS tile transpose. z selects Wq/Wk/Wv.
__global__ __launch_bounds__(256) void cvt_wt(const float* __restrict__ Wq,
                                              const float* __restrict__ Wk,
                                              const float* __restrict__ Wv,
                                              unsigned short* __restrict__ WT) {
  const int z = blockIdx.z;
  const float* W = (z == 0) ? Wq : (z == 1) ? Wk : Wv;
  __shared__ float tile[32][33];
  const int k0 = blockIdx.y * 32, n0 = blockIdx.x * 32;
  const int tx = threadIdx.x & 31, ty = threadIdx.x >> 5;   // ty 0..7
  for (int i = 0; i < 4; ++i)
    tile[ty + i * 8][tx] = W[(size_t)(k0 + ty + i * 8) * D_MODEL + n0 + tx];
  __syncthreads();
  unsigned short* out = WT + (size_t)z * D_MODEL * D_MODEL;
  for (int i = 0; i < 4; ++i)
    out[(size_t)(n0 + ty + i * 8) * D_MODEL + k0 + tx] = f2bf(tile[tx][ty + i * 8]);
}

// ---------------------------------------------------------------- gemm_qkv
// C[m,n] = Qbf[m,:] . WT[n,:]  (+bias). 128x128 tile, BK=32, global_load_lds 16B.
// z=0: write q_a fp32 to out_qa; z=1: K bf16 to kbf; z=2: V bf16 to vbf.
#define BM 128
#define BN 128
#define BK 32

__global__ __launch_bounds__(256, 2) void gemm_qkv(
    const unsigned short* __restrict__ Qbf,
    const unsigned short* __restrict__ WT,
    const float* __restrict__ bq_p, const float* __restrict__ bk_p,
    const float* __restrict__ bv_p,
    float* __restrict__ out_qa,
    unsigned short* __restrict__ kbf,
    unsigned short* __restrict__ vbf) {
  const int z  = blockIdx.z;
  const int n0 = blockIdx.x * BN;
  const int m0 = blockIdx.y * BM;
  const int K  = D_MODEL;

  __shared__ unsigned short smA[BM * BK];
  __shared__ unsigned short smB[BN * BK];

  const int t    = threadIdx.x;
  const int lane = t & 63;
  const int w    = t >> 6;
  const int quad = lane >> 4;
  const int l16  = lane & 15;
  const int wr   = w >> 1, wc = w & 1;

  const unsigned short* Wz = WT + (size_t)z * D_MODEL * D_MODEL;

  f32x4 acc[4][4];
  for (int i = 0; i < 4; ++i)
    for (int j = 0; j < 4; ++j) acc[i][j] = (f32x4){0.f, 0.f, 0.f, 0.f};

  for (int k0 = 0; k0 < K; k0 += BK) {
    __syncthreads();  // prev iter LDS reads done before overwrite
    // stage A[128][32] and B[128][32] bf16: 512 chunks of 16B each, 2/thread
    for (int it = 0; it < 2; ++it) {
      int c   = t + it * 256;
      int row = c >> 2, col = (c & 3) * 8;
      const unsigned short* ga = Qbf + (size_t)(m0 + row) * K + k0 + col;
      const unsigned short* gb = Wz  + (size_t)(n0 + row) * K + k0 + col;
      __builtin_amdgcn_global_load_lds(
          (const __attribute__((address_space(1))) void*)ga,
          (__attribute__((address_space(3))) void*)&smA[c * 8], 16, 0, 0);
      __builtin_amdgcn_global_load_lds(
          (const __attribute__((address_space(1))) void*)gb,
          (__attribute__((address_space(3))) void*)&smB[c * 8], 16, 0, 0);
    }
    __syncthreads();  // staging visible (implies vmcnt(0) drain)

    short8 afr[4], bfr[4];
    for (int mi = 0; mi < 4; ++mi)
      afr[mi] = *(const short8*)&smA[(wr * 64 + mi * 16 + l16) * BK + quad * 8];
    for (int ni = 0; ni < 4; ++ni)
      bfr[ni] = *(const short8*)&smB[(wc * 64 + ni * 16 + l16) * BK + quad * 8];
    for (int mi = 0; mi < 4; ++mi)
      for (int ni = 0; ni < 4; ++ni)
        acc[mi][ni] = __builtin_amdgcn_mfma_f32_16x16x32_bf16(
            afr[mi], bfr[ni], acc[mi][ni], 0, 0, 0);
  }

  // epilogue: C-layout col = lane&15, row = quad*4 + reg
  const float* bias = (z == 0) ? bq_p : (z == 1) ? bk_p : bv_p;
  for (int ni = 0; ni < 4; ++ni) {
    int n = n0 + wc * 64 + ni * 16 + l16;
    float bval = bias[n];
    for (int mi = 0; mi < 4; ++mi) {
      int mbase = m0 + wr * 64 + mi * 16 + quad * 4;
      for (int j = 0; j < 4; ++j) {
        float v = acc[mi][ni][j] + bval;
        size_t idx = (size_t)(mbase + j) * D_MODEL + n;
        if (z == 0)      out_qa[idx] = v;
        else if (z == 1) kbf[idx] = f2bf(v);
        else             vbf[idx] = f2bf(v);
      }
    }
  }
}

// ---------------------------------------------------------------- attn
// One block per (query-tile of 64, b, h). 4 waves; wave w owns 16 query rows.
// Streaming exp-attention (no max shift, faithful to reference):
//   num += exp(s)*V, den += exp(s); masked keys contribute 0.
__global__ __launch_bounds__(256, 2) void attn(
    const float* __restrict__ qa,            // [8192,1024] fp32
    const unsigned short* __restrict__ kbf,  // [8192,1024] bf16
    const unsigned short* __restrict__ vbf,  // [8192,1024] bf16
    const int* __restrict__ length,
    float* __restrict__ ctx) {               // [8192,1024] fp32
  const int qt = blockIdx.x;            // 0..31
  const int bh = blockIdx.y;            // 0..63
  const int b = bh >> 4, h = bh & 15;
  const int len = length[b];

  const int t    = threadIdx.x;
  const int lane = t & 63;
  const int w    = t >> 6;
  const int quad = lane >> 4;
  const int l16  = lane & 15;

  __shared__ unsigned short sQ[64 * 64];    // [q][d]
  __shared__ unsigned short sK[64 * 64];    // [k][d]
  __shared__ unsigned short sVT[64 * 64];   // [d][k]
  __shared__ unsigned short sP[64 * 64];    // [q][k] per-wave strips

  // stage Q tile (fp32 -> bf16): thread t -> row t>>2, 16 cols at (t&3)*16
  {
    int r = t >> 2, c0 = (t & 3) * 16;
    const float* src = qa + (size_t)(b * SEQ + qt * 64 + r) * D_MODEL + h * D_KH + c0;
    unsigned short* dst = &sQ[r * 64 + c0];
    for (int i = 0; i < 4; ++i) {
      float4 v = *(const float4*)(src + i * 4);
      dst[i * 4 + 0] = f2bf(v.x); dst[i * 4 + 1] = f2bf(v.y);
      dst[i * 4 + 2] = f2bf(v.z); dst[i * 4 + 3] = f2bf(v.w);
    }
  }

  f32x4 accpv[4];
  for (int i = 0; i < 4; ++i) accpv[i] = (f32x4){0.f, 0.f, 0.f, 0.f};
  float den[4] = {0.f, 0.f, 0.f, 0.f};

  const int nkt = (len + 63) >> 6;
  for (int kt = 0; kt < nkt; ++kt) {
    __syncthreads();  // all readers of sK/sVT (and kt==0: pre-staging) done
    {
      int r = t >> 2, c0 = (t & 3) * 16;
      size_t rowoff = (size_t)(b * SEQ + kt * 64 + r) * D_MODEL + h * D_KH + c0;
      // K: straight bf16 copy (rows contiguous -> B-operand friendly)
      *(short8*)&sK[r * 64 + c0]     = *(const short8*)(kbf + rowoff);
      *(short8*)&sK[r * 64 + c0 + 8] = *(const short8*)(kbf + rowoff + 8);
      // V: transpose into sVT[d][k]
      short8 v0 = *(const short8*)(vbf + rowoff);
      short8 v1 = *(const short8*)(vbf + rowoff + 8);
      for (int i = 0; i < 8; ++i) sVT[(c0 + i) * 64 + r]     = (unsigned short)v0[i];
      for (int i = 0; i < 8; ++i) sVT[(c0 + 8 + i) * 64 + r] = (unsigned short)v1[i];
    }
    __syncthreads();  // staging visible

    // QK^T: wave's 16 queries x 64 keys
    short8 qa0 = *(const short8*)&sQ[(w * 16 + l16) * 64 + quad * 8];
    short8 qa1 = *(const short8*)&sQ[(w * 16 + l16) * 64 + 32 + quad * 8];
    for (int n = 0; n < 4; ++n) {
      f32x4 s = (f32x4){0.f, 0.f, 0.f, 0.f};
      short8 kb0 = *(const short8*)&sK[(n * 16 + l16) * 64 + quad * 8];
      short8 kb1 = *(const short8*)&sK[(n * 16 + l16) * 64 + 32 + quad * 8];
      s = __builtin_amdgcn_mfma_f32_16x16x32_bf16(qa0, kb0, s, 0, 0, 0);
      s = __builtin_amdgcn_mfma_f32_16x16x32_bf16(qa1, kb1, s, 0, 0, 0);
      int key = kt * 64 + n * 16 + l16;
      bool valid = key < len;
      for (int j = 0; j < 4; ++j) {
        float e = valid ? __expf(s[j] * 0.125f) : 0.f;  // 1/sqrt(64)=0.125
        den[j] += e;
        sP[(w * 16 + quad * 4 + j) * 64 + n * 16 + l16] = f2bf(e);
      }
    }
    // NOTE: sP strip is private to this wave -> no barrier needed before PV.

    // PV: accpv[16q x 64d] += P[16q x 64k] @ V[64k x 64d]
    short8 pa0 = *(const short8*)&sP[(w * 16 + l16) * 64 + quad * 8];
    short8 pa1 = *(const short8*)&sP[(w * 16 + l16) * 64 + 32 + quad * 8];
    for (int n2 = 0; n2 < 4; ++n2) {
      short8 vb0 = *(const short8*)&sVT[(n2 * 16 + l16) * 64 + quad * 8];
      short8 vb1 = *(const short8*)&sVT[(n2 * 16 + l16) * 64 + 32 + quad * 8];
      accpv[n2] = __builtin_amdgcn_mfma_f32_16x16x32_bf16(pa0, vb0, accpv[n2], 0, 0, 0);
      accpv[n2] = __builtin_amdgcn_mfma_f32_16x16x32_bf16(pa1, vb1, accpv[n2], 0, 0, 0);
    }
  }

  // reduce den over the 16 column-lanes (rows are quad*4+j)
  float inv[4];
  for (int j = 0; j < 4; ++j) {
    float d = den[j];
    d += __shfl_xor(d, 1, 64);
    d += __shfl_xor(d, 2, 64);
    d += __shfl_xor(d, 4, 64);
    d += __shfl_xor(d, 8, 64);
    inv[j] = 1.f / (d + 1e-8f);
  }
  for (int n2 = 0; n2 < 4; ++n2)
    for (int j = 0; j < 4; ++j) {
      int q = qt * 64 + w * 16 + quad * 4 + j;
      int d = h * D_KH + n2 * 16 + l16;
      ctx[(size_t)(b * SEQ + q) * D_MODEL + d] = accpv[n2][j] * inv[j];
    }
}

// ---------------------------------------------------------------- launch
extern "C" void kernel_launch(void* const* d_in, const int* in_sizes, int n_in,
                              void* d_out, int out_size, void* d_ws, size_t ws_size,
                              hipStream_t stream) {
  const float* Q      = (const float*)d_in[0];
  const int*   length = (const int*)d_in[1];
  const float* Wq     = (const float*)d_in[2];
  const float* bq     = (const float*)d_in[3];
  const float* Wk     = (const float*)d_in[4];
  const float* bk     = (const float*)d_in[5];
  const float* Wv     = (const float*)d_in[6];
  const float* bv     = (const float*)d_in[7];

  float* out_ctx = (float*)d_out;                         // [8192,1024]
  float* out_qa  = out_ctx + (size_t)M_TOTAL * D_MODEL;   // [8192,1024]

  char* ws = (char*)d_ws;
  unsigned short* Qbf = (unsigned short*)ws;                              // 16 MB
  unsigned short* WT  = (unsigned short*)(ws + (size_t)16 * 1024 * 1024); //  6 MB
  unsigned short* Kbf = (unsigned short*)(ws + (size_t)22 * 1024 * 1024); // 16 MB
  unsigned short* Vbf = (unsigned short*)(ws + (size_t)38 * 1024 * 1024); // 16 MB

  hipLaunchKernelGGL(cvt_q, dim3((M_TOTAL * D_MODEL) / (256 * 4)), dim3(256), 0, stream,
                     Q, Qbf);
  hipLaunchKernelGGL(cvt_wt, dim3(32, 32, 3), dim3(256), 0, stream, Wq, Wk, Wv, WT);
  hipLaunchKernelGGL(gemm_qkv, dim3(D_MODEL / BN, M_TOTAL / BM, 3), dim3(256), 0, stream,
                     Qbf, WT, bq, bk, bv, out_qa, Kbf, Vbf);
  hipLaunchKernelGGL(attn, dim3(SEQ / 64, BATCH * N_HEADS), dim3(256), 0, stream,
                     out_qa, Kbf, Vbf, length, out_ctx);
}

// Round 2
// 300.227 us; speedup vs baseline: 1.0905x; 1.0905x over previous
//
#include <hip/hip_runtime.h>

#define D_MODEL 1024
#define N_HEADS 16
#define D_KH    64
#define BATCH   4
#define SEQ     2048
#define M_TOTAL (BATCH*SEQ)   // 8192

typedef __attribute__((ext_vector_type(8))) short short8;
typedef __attribute__((ext_vector_type(4))) float f32x4;
typedef __attribute__((ext_vector_type(4))) unsigned short u16x4;

__device__ __forceinline__ unsigned short f2bf(float f) {
  union { float f; unsigned u; } v; v.f = f;
  unsigned r = v.u + 0x7FFFu + ((v.u >> 16) & 1u);
  return (unsigned short)(r >> 16);
}

// ---------------------------------------------------------------- cvt_q
__global__ __launch_bounds__(256) void cvt_q(const float* __restrict__ Q,
                                             unsigned short* __restrict__ Qbf) {
  size_t i = (size_t)blockIdx.x * 256 + threadIdx.x;
  float4 v = ((const float4*)Q)[i];
  u16x4 o;
  o[0] = f2bf(v.x); o[1] = f2bf(v.y); o[2] = f2bf(v.z); o[3] = f2bf(v.w);
  ((u16x4*)Qbf)[i] = o;
}

// ---------------------------------------------------------------- cvt_wt
__global__ __launch_bounds__(256) void cvt_wt(const float* __restrict__ Wq,
                                              const float* __restrict__ Wk,
                                              const float* __restrict__ Wv,
                                              unsigned short* __restrict__ WT) {
  const int z = blockIdx.z;
  const float* W = (z == 0) ? Wq : (z == 1) ? Wk : Wv;
  __shared__ float tile[32][33];
  const int k0 = blockIdx.y * 32, n0 = blockIdx.x * 32;
  const int tx = threadIdx.x & 31, ty = threadIdx.x >> 5;
  for (int i = 0; i < 4; ++i)
    tile[ty + i * 8][tx] = W[(size_t)(k0 + ty + i * 8) * D_MODEL + n0 + tx];
  __syncthreads();
  unsigned short* out = WT + (size_t)z * D_MODEL * D_MODEL;
  for (int i = 0; i < 4; ++i)
    out[(size_t)(n0 + ty + i * 8) * D_MODEL + k0 + tx] = f2bf(tile[tx][ty + i * 8]);
}

// ---------------------------------------------------------------- gemm_qkv
// z=0: q_a fp32 -> out_qa [8192,1024]
// z=1: K bf16   -> kbf    [8192,1024]            (row-major tokens x d_model)
// z=2: V bf16   -> vt     [(b*16+h)*64+d][2048]  (TRANSPOSED per head)
#define BM 128
#define BN 128
#define BK 32

__global__ __launch_bounds__(256, 2) void gemm_qkv(
    const unsigned short* __restrict__ Qbf,
    const unsigned short* __restrict__ WT,
    const float* __restrict__ bq_p, const float* __restrict__ bk_p,
    const float* __restrict__ bv_p,
    float* __restrict__ out_qa,
    unsigned short* __restrict__ kbf,
    unsigned short* __restrict__ vt) {
  const int z  = blockIdx.z;
  const int n0 = blockIdx.x * BN;
  const int m0 = blockIdx.y * BM;
  const int K  = D_MODEL;

  __shared__ unsigned short smA[BM * BK];
  __shared__ unsigned short smB[BN * BK];

  const int t    = threadIdx.x;
  const int lane = t & 63;
  const int w    = t >> 6;
  const int quad = lane >> 4;
  const int l16  = lane & 15;
  const int wr   = w >> 1, wc = w & 1;

  const unsigned short* Wz = WT + (size_t)z * D_MODEL * D_MODEL;

  f32x4 acc[4][4];
  for (int i = 0; i < 4; ++i)
    for (int j = 0; j < 4; ++j) acc[i][j] = (f32x4){0.f, 0.f, 0.f, 0.f};

  for (int k0 = 0; k0 < K; k0 += BK) {
    __syncthreads();
    for (int it = 0; it < 2; ++it) {
      int c   = t + it * 256;
      int row = c >> 2, col = (c & 3) * 8;
      const unsigned short* ga = Qbf + (size_t)(m0 + row) * K + k0 + col;
      const unsigned short* gb = Wz  + (size_t)(n0 + row) * K + k0 + col;
      __builtin_amdgcn_global_load_lds(
          (const __attribute__((address_space(1))) void*)ga,
          (__attribute__((address_space(3))) void*)&smA[c * 8], 16, 0, 0);
      __builtin_amdgcn_global_load_lds(
          (const __attribute__((address_space(1))) void*)gb,
          (__attribute__((address_space(3))) void*)&smB[c * 8], 16, 0, 0);
    }
    __syncthreads();

    short8 afr[4], bfr[4];
    for (int mi = 0; mi < 4; ++mi)
      afr[mi] = *(const short8*)&smA[(wr * 64 + mi * 16 + l16) * BK + quad * 8];
    for (int ni = 0; ni < 4; ++ni)
      bfr[ni] = *(const short8*)&smB[(wc * 64 + ni * 16 + l16) * BK + quad * 8];
    for (int mi = 0; mi < 4; ++mi)
      for (int ni = 0; ni < 4; ++ni)
        acc[mi][ni] = __builtin_amdgcn_mfma_f32_16x16x32_bf16(
            afr[mi], bfr[ni], acc[mi][ni], 0, 0, 0);
  }

  // epilogue: C-layout col = lane&15 (n), rows = quad*4 + j (m)
  const float* bias = (z == 0) ? bq_p : (z == 1) ? bk_p : bv_p;
  if (z == 2) {
    // V transposed per head: vt[((b*16+h)*64 + d)*2048 + s], 4 consecutive s per lane
    for (int ni = 0; ni < 4; ++ni) {
      int n = n0 + wc * 64 + ni * 16 + l16;
      float bval = bias[n];
      int h = n >> 6, d = n & 63;
      for (int mi = 0; mi < 4; ++mi) {
        int m = m0 + wr * 64 + mi * 16 + quad * 4;
        int b = m >> 11, s = m & 2047;
        u16x4 o;
        for (int j = 0; j < 4; ++j) o[j] = f2bf(acc[mi][ni][j] + bval);
        *(u16x4*)&vt[(size_t)((b * 16 + h) * 64 + d) * SEQ + s] = o;
      }
    }
  } else {
    for (int ni = 0; ni < 4; ++ni) {
      int n = n0 + wc * 64 + ni * 16 + l16;
      float bval = bias[n];
      for (int mi = 0; mi < 4; ++mi) {
        int mbase = m0 + wr * 64 + mi * 16 + quad * 4;
        for (int j = 0; j < 4; ++j) {
          float v = acc[mi][ni][j] + bval;
          size_t idx = (size_t)(mbase + j) * D_MODEL + n;
          if (z == 0) out_qa[idx] = v;
          else        kbf[idx] = f2bf(v);
        }
      }
    }
  }
}

// ---------------------------------------------------------------- attn
#define PSTR 72   // sP row stride in elements (144 B = 16*9: b128-aligned, 2-way max)

__global__ __launch_bounds__(256, 2) void attn(
    const float* __restrict__ qa,            // [8192,1024] fp32
    const unsigned short* __restrict__ kbf,  // [8192,1024] bf16
    const unsigned short* __restrict__ vt,   // [(bh)*64+d][2048] bf16 (V^T per head)
    const int* __restrict__ length,
    float* __restrict__ ctx) {               // [8192,1024] fp32
  const int qt = blockIdx.x;            // 0..31
  const int bh = blockIdx.y;            // 0..63
  const int b = bh >> 4, h = bh & 15;
  const int len = length[b];

  const int t    = threadIdx.x;
  const int lane = t & 63;
  const int w    = t >> 6;
  const int quad = lane >> 4;
  const int l16  = lane & 15;

  __shared__ unsigned short sQ[64 * 64];     // [q][d]
  __shared__ unsigned short sK[64 * 64];     // [k][d]
  __shared__ unsigned short sVT[64 * 64];    // [d][k]  (direct copy from vt)
  __shared__ unsigned short sP[64 * PSTR];   // [q][k] padded

  // stage Q tile (fp32 -> bf16)
  {
    int r = t >> 2, c0 = (t & 3) * 16;
    const float* src = qa + (size_t)(b * SEQ + qt * 64 + r) * D_MODEL + h * D_KH + c0;
    unsigned short* dst = &sQ[r * 64 + c0];
    for (int i = 0; i < 4; ++i) {
      float4 v = *(const float4*)(src + i * 4);
      dst[i * 4 + 0] = f2bf(v.x); dst[i * 4 + 1] = f2bf(v.y);
      dst[i * 4 + 2] = f2bf(v.z); dst[i * 4 + 3] = f2bf(v.w);
    }
  }

  f32x4 accpv[4];
  for (int i = 0; i < 4; ++i) accpv[i] = (f32x4){0.f, 0.f, 0.f, 0.f};
  float den[4] = {0.f, 0.f, 0.f, 0.f};

  const float SCL = 0.125f * 1.44269504f;    // 1/sqrt(64) * log2(e)

  const int nkt = (len + 63) >> 6;
  for (int kt = 0; kt < nkt; ++kt) {
    __syncthreads();
    {
      int r = t >> 2, c0 = (t & 3) * 16;
      // K rows: [key][d]
      size_t koff = (size_t)(b * SEQ + kt * 64 + r) * D_MODEL + h * D_KH + c0;
      *(short8*)&sK[r * 64 + c0]     = *(const short8*)(kbf + koff);
      *(short8*)&sK[r * 64 + c0 + 8] = *(const short8*)(kbf + koff + 8);
      // V^T rows: [d][s] — straight copy, no transpose
      size_t voff = (size_t)(bh * 64 + r) * SEQ + kt * 64 + c0;
      *(short8*)&sVT[r * 64 + c0]     = *(const short8*)(vt + voff);
      *(short8*)&sVT[r * 64 + c0 + 8] = *(const short8*)(vt + voff + 8);
    }
    __syncthreads();

    // QK^T: wave's 16 queries x 64 keys
    short8 qa0 = *(const short8*)&sQ[(w * 16 + l16) * 64 + quad * 8];
    short8 qa1 = *(const short8*)&sQ[(w * 16 + l16) * 64 + 32 + quad * 8];
    for (int n = 0; n < 4; ++n) {
      f32x4 s = (f32x4){0.f, 0.f, 0.f, 0.f};
      short8 kb0 = *(const short8*)&sK[(n * 16 + l16) * 64 + quad * 8];
      short8 kb1 = *(const short8*)&sK[(n * 16 + l16) * 64 + 32 + quad * 8];
      s = __builtin_amdgcn_mfma_f32_16x16x32_bf16(qa0, kb0, s, 0, 0, 0);
      s = __builtin_amdgcn_mfma_f32_16x16x32_bf16(qa1, kb1, s, 0, 0, 0);
      int key = kt * 64 + n * 16 + l16;
      bool valid = key < len;
      for (int j = 0; j < 4; ++j) {
        float e = valid ? exp2f(s[j] * SCL) : 0.f;
        den[j] += e;
        sP[(w * 16 + quad * 4 + j) * PSTR + n * 16 + l16] = f2bf(e);
      }
    }
    // sP strip private to this wave -> no barrier before PV

    short8 pa0 = *(const short8*)&sP[(w * 16 + l16) * PSTR + quad * 8];
    short8 pa1 = *(const short8*)&sP[(w * 16 + l16) * PSTR + 32 + quad * 8];
    for (int n2 = 0; n2 < 4; ++n2) {
      short8 vb0 = *(const short8*)&sVT[(n2 * 16 + l16) * 64 + quad * 8];
      short8 vb1 = *(const short8*)&sVT[(n2 * 16 + l16) * 64 + 32 + quad * 8];
      accpv[n2] = __builtin_amdgcn_mfma_f32_16x16x32_bf16(pa0, vb0, accpv[n2], 0, 0, 0);
      accpv[n2] = __builtin_amdgcn_mfma_f32_16x16x32_bf16(pa1, vb1, accpv[n2], 0, 0, 0);
    }
  }

  float inv[4];
  for (int j = 0; j < 4; ++j) {
    float d = den[j];
    d += __shfl_xor(d, 1, 64);
    d += __shfl_xor(d, 2, 64);
    d += __shfl_xor(d, 4, 64);
    d += __shfl_xor(d, 8, 64);
    inv[j] = 1.f / (d + 1e-8f);
  }
  for (int n2 = 0; n2 < 4; ++n2)
    for (int j = 0; j < 4; ++j) {
      int q = qt * 64 + w * 16 + quad * 4 + j;
      int d = h * D_KH + n2 * 16 + l16;
      ctx[(size_t)(b * SEQ + q) * D_MODEL + d] = accpv[n2][j] * inv[j];
    }
}

// ---------------------------------------------------------------- launch
extern "C" void kernel_launch(void* const* d_in, const int* in_sizes, int n_in,
                              void* d_out, int out_size, void* d_ws, size_t ws_size,
                              hipStream_t stream) {
  const float* Q      = (const float*)d_in[0];
  const int*   length = (const int*)d_in[1];
  const float* Wq     = (const float*)d_in[2];
  const float* bq     = (const float*)d_in[3];
  const float* Wk     = (const float*)d_in[4];
  const float* bk     = (const float*)d_in[5];
  const float* Wv     = (const float*)d_in[6];
  const float* bv     = (const float*)d_in[7];

  float* out_ctx = (float*)d_out;                         // [8192,1024]
  float* out_qa  = out_ctx + (size_t)M_TOTAL * D_MODEL;   // [8192,1024]

  char* ws = (char*)d_ws;
  unsigned short* Qbf = (unsigned short*)ws;                              // 16 MB
  unsigned short* WT  = (unsigned short*)(ws + (size_t)16 * 1024 * 1024); //  6 MB
  unsigned short* Kbf = (unsigned short*)(ws + (size_t)22 * 1024 * 1024); // 16 MB
  unsigned short* Vt  = (unsigned short*)(ws + (size_t)38 * 1024 * 1024); // 16 MB

  hipLaunchKernelGGL(cvt_q, dim3((M_TOTAL * D_MODEL) / (256 * 4)), dim3(256), 0, stream,
                     Q, Qbf);
  hipLaunchKernelGGL(cvt_wt, dim3(32, 32, 3), dim3(256), 0, stream, Wq, Wk, Wv, WT);
  hipLaunchKernelGGL(gemm_qkv, dim3(D_MODEL / BN, M_TOTAL / BM, 3), dim3(256), 0, stream,
                     Qbf, WT, bq, bk, bv, out_qa, Kbf, Vt);
  hipLaunchKernelGGL(attn, dim3(SEQ / 64, BATCH * N_HEADS), dim3(256), 0, stream,
                     out_qa, Kbf, Vt, length, out_ctx);
}

// Round 3
// 261.128 us; speedup vs baseline: 1.2538x; 1.1497x over previous
//
#include <hip/hip_runtime.h>

#define D_MODEL 1024
#define N_HEADS 16
#define D_KH    64
#define BATCH   4
#define SEQ     2048
#define M_TOTAL (BATCH*SEQ)   // 8192

typedef __attribute__((ext_vector_type(8))) short short8;
typedef __attribute__((ext_vector_type(4))) float f32x4;
typedef __attribute__((ext_vector_type(4))) unsigned short u16x4;
typedef __attribute__((ext_vector_type(2))) unsigned int u32x2;

__device__ __forceinline__ unsigned short f2bf(float f) {
  union { float f; unsigned u; } v; v.f = f;
  unsigned r = v.u + 0x7FFFu + ((v.u >> 16) & 1u);
  return (unsigned short)(r >> 16);
}
__device__ __forceinline__ unsigned fbits(float f) {
  union { float f; unsigned u; } v; v.f = f; return v.u;
}

// ---------------------------------------------------------------- cvt_q
__global__ __launch_bounds__(256) void cvt_q(const float* __restrict__ Q,
                                             unsigned short* __restrict__ Qbf) {
  size_t i = (size_t)blockIdx.x * 256 + threadIdx.x;
  float4 v = ((const float4*)Q)[i];
  u16x4 o;
  o[0] = f2bf(v.x); o[1] = f2bf(v.y); o[2] = f2bf(v.z); o[3] = f2bf(v.w);
  ((u16x4*)Qbf)[i] = o;
}

// ---------------------------------------------------------------- cvt_wt
__global__ __launch_bounds__(256) void cvt_wt(const float* __restrict__ Wq,
                                              const float* __restrict__ Wk,
                                              const float* __restrict__ Wv,
                                              unsigned short* __restrict__ WT) {
  const int z = blockIdx.z;
  const float* W = (z == 0) ? Wq : (z == 1) ? Wk : Wv;
  __shared__ float tile[32][33];
  const int k0 = blockIdx.y * 32, n0 = blockIdx.x * 32;
  const int tx = threadIdx.x & 31, ty = threadIdx.x >> 5;
  for (int i = 0; i < 4; ++i)
    tile[ty + i * 8][tx] = W[(size_t)(k0 + ty + i * 8) * D_MODEL + n0 + tx];
  __syncthreads();
  unsigned short* out = WT + (size_t)z * D_MODEL * D_MODEL;
  for (int i = 0; i < 4; ++i)
    out[(size_t)(n0 + ty + i * 8) * D_MODEL + k0 + tx] = f2bf(tile[tx][ty + i * 8]);
}

// ---------------------------------------------------------------- gemm_qkv
// z=0: q_a fp32 -> out_qa [8192,1024]
// z=1: K bf16   -> kbf    [8192,1024]
// z=2: V bf16   -> vt     [(b*16+h)*64+d][2048]  (transposed per head)
#define BM 128
#define BN 128
#define BK 32

__global__ __launch_bounds__(256, 2) void gemm_qkv(
    const unsigned short* __restrict__ Qbf,
    const unsigned short* __restrict__ WT,
    const float* __restrict__ bq_p, const float* __restrict__ bk_p,
    const float* __restrict__ bv_p,
    float* __restrict__ out_qa,
    unsigned short* __restrict__ kbf,
    unsigned short* __restrict__ vt) {
  const int z  = blockIdx.z;
  const int n0 = blockIdx.x * BN;
  const int m0 = blockIdx.y * BM;
  const int K  = D_MODEL;

  __shared__ unsigned short smA[BM * BK];
  __shared__ unsigned short smB[BN * BK];

  const int t    = threadIdx.x;
  const int lane = t & 63;
  const int w    = t >> 6;
  const int quad = lane >> 4;
  const int l16  = lane & 15;
  const int wr   = w >> 1, wc = w & 1;

  const unsigned short* Wz = WT + (size_t)z * D_MODEL * D_MODEL;

  f32x4 acc[4][4];
  for (int i = 0; i < 4; ++i)
    for (int j = 0; j < 4; ++j) acc[i][j] = (f32x4){0.f, 0.f, 0.f, 0.f};

  for (int k0 = 0; k0 < K; k0 += BK) {
    __syncthreads();
    for (int it = 0; it < 2; ++it) {
      int c   = t + it * 256;
      int row = c >> 2, col = (c & 3) * 8;
      const unsigned short* ga = Qbf + (size_t)(m0 + row) * K + k0 + col;
      const unsigned short* gb = Wz  + (size_t)(n0 + row) * K + k0 + col;
      __builtin_amdgcn_global_load_lds(
          (const __attribute__((address_space(1))) void*)ga,
          (__attribute__((address_space(3))) void*)&smA[c * 8], 16, 0, 0);
      __builtin_amdgcn_global_load_lds(
          (const __attribute__((address_space(1))) void*)gb,
          (__attribute__((address_space(3))) void*)&smB[c * 8], 16, 0, 0);
    }
    __syncthreads();

    short8 afr[4], bfr[4];
    for (int mi = 0; mi < 4; ++mi)
      afr[mi] = *(const short8*)&smA[(wr * 64 + mi * 16 + l16) * BK + quad * 8];
    for (int ni = 0; ni < 4; ++ni)
      bfr[ni] = *(const short8*)&smB[(wc * 64 + ni * 16 + l16) * BK + quad * 8];
    for (int mi = 0; mi < 4; ++mi)
      for (int ni = 0; ni < 4; ++ni)
        acc[mi][ni] = __builtin_amdgcn_mfma_f32_16x16x32_bf16(
            afr[mi], bfr[ni], acc[mi][ni], 0, 0, 0);
  }

  const float* bias = (z == 0) ? bq_p : (z == 1) ? bk_p : bv_p;
  if (z == 2) {
    for (int ni = 0; ni < 4; ++ni) {
      int n = n0 + wc * 64 + ni * 16 + l16;
      float bval = bias[n];
      int h = n >> 6, d = n & 63;
      for (int mi = 0; mi < 4; ++mi) {
        int m = m0 + wr * 64 + mi * 16 + quad * 4;
        int b = m >> 11, s = m & 2047;
        u16x4 o;
        for (int j = 0; j < 4; ++j) o[j] = f2bf(acc[mi][ni][j] + bval);
        *(u16x4*)&vt[(size_t)((b * 16 + h) * 64 + d) * SEQ + s] = o;
      }
    }
  } else {
    for (int ni = 0; ni < 4; ++ni) {
      int n = n0 + wc * 64 + ni * 16 + l16;
      float bval = bias[n];
      for (int mi = 0; mi < 4; ++mi) {
        int mbase = m0 + wr * 64 + mi * 16 + quad * 4;
        for (int j = 0; j < 4; ++j) {
          float v = acc[mi][ni][j] + bval;
          size_t idx = (size_t)(mbase + j) * D_MODEL + n;
          if (z == 0) out_qa[idx] = v;
          else        kbf[idx] = f2bf(v);
        }
      }
    }
  }
}

// ---------------------------------------------------------------- attn
#define PST 72   // LDS row stride (elements); 144 B -> bank group (row+colblk)%8

__global__ __launch_bounds__(256, 2) void attn(
    const float* __restrict__ qa,            // [8192,1024] fp32
    const unsigned short* __restrict__ kbf,  // [8192,1024] bf16
    const unsigned short* __restrict__ vt,   // [(bh)*64+d][2048] bf16 (V^T)
    const int* __restrict__ length,
    float* __restrict__ ctx) {               // [8192,1024] fp32
  const int qt = blockIdx.x;            // 0..31
  const int bh = blockIdx.y;            // 0..63
  const int b = bh >> 4, h = bh & 15;
  const int len = length[b];

  const int t    = threadIdx.x;
  const int lane = t & 63;
  const int w    = t >> 6;
  const int quad = lane >> 4;
  const int l16  = lane & 15;
  const int r8   = t >> 3;              // 0..31
  const int c8   = (t & 7) * 8;         // 0,8,..,56

  __shared__ unsigned short sQ[64 * PST];   // [q][d]
  __shared__ unsigned short sK[64 * PST];   // [k][d]
  __shared__ unsigned short sVT[64 * PST];  // [d][k]
  __shared__ unsigned short sP[64 * PST];   // [q][k]

  // stage Q tile (fp32 -> bf16), one short8 per thread per half
  for (int half = 0; half < 2; ++half) {
    int r = r8 + half * 32;
    const float* src = qa + (size_t)(b * SEQ + qt * 64 + r) * D_MODEL + h * D_KH + c8;
    float4 v0 = *(const float4*)src;
    float4 v1 = *(const float4*)(src + 4);
    short8 o;
    o[0] = (short)f2bf(v0.x); o[1] = (short)f2bf(v0.y);
    o[2] = (short)f2bf(v0.z); o[3] = (short)f2bf(v0.w);
    o[4] = (short)f2bf(v1.x); o[5] = (short)f2bf(v1.y);
    o[6] = (short)f2bf(v1.z); o[7] = (short)f2bf(v1.w);
    *(short8*)&sQ[r * PST + c8] = o;
  }
  __syncthreads();

  // loop-invariant Q fragments (B-operand of S^T = K.Q^T)
  short8 qf0 = *(const short8*)&sQ[(w * 16 + l16) * PST + quad * 8];
  short8 qf1 = *(const short8*)&sQ[(w * 16 + l16) * PST + 32 + quad * 8];

  f32x4 accpv[4];
  for (int i = 0; i < 4; ++i) accpv[i] = (f32x4){0.f, 0.f, 0.f, 0.f};
  float den = 0.f;                      // per-lane partial for query l16

  const float SCL = 0.125f * 1.44269504f;    // 1/sqrt(64) * log2(e)

  const int nkt = (len + 63) >> 6;
  for (int kt = 0; kt < nkt; ++kt) {
    __syncthreads();   // prev-iter readers of sK/sVT done
    for (int half = 0; half < 2; ++half) {
      int r = r8 + half * 32;
      size_t koff = (size_t)(b * SEQ + kt * 64 + r) * D_MODEL + h * D_KH + c8;
      *(short8*)&sK[r * PST + c8] = *(const short8*)(kbf + koff);
      size_t voff = (size_t)(bh * 64 + r) * SEQ + kt * 64 + c8;
      *(short8*)&sVT[r * PST + c8] = *(const short8*)(vt + voff);
    }
    __syncthreads();   // staging visible

    // S^T = K.Q^T : per n-block of 16 keys, D[key=quad*4+j][q=l16]
    for (int n = 0; n < 4; ++n) {
      short8 kf0 = *(const short8*)&sK[(n * 16 + l16) * PST + quad * 8];
      short8 kf1 = *(const short8*)&sK[(n * 16 + l16) * PST + 32 + quad * 8];
      f32x4 s = (f32x4){0.f, 0.f, 0.f, 0.f};
      s = __builtin_amdgcn_mfma_f32_16x16x32_bf16(kf0, qf0, s, 0, 0, 0);
      s = __builtin_amdgcn_mfma_f32_16x16x32_bf16(kf1, qf1, s, 0, 0, 0);
      int kbase = kt * 64 + n * 16 + quad * 4;
      float e0 = (kbase + 0 < len) ? exp2f(s[0] * SCL) : 0.f;
      float e1 = (kbase + 1 < len) ? exp2f(s[1] * SCL) : 0.f;
      float e2 = (kbase + 2 < len) ? exp2f(s[2] * SCL) : 0.f;
      float e3 = (kbase + 3 < len) ? exp2f(s[3] * SCL) : 0.f;
      den += (e0 + e1) + (e2 + e3);
      // pack 4 consecutive keys (truncate to bf16) -> one b64 write
      u32x2 pk;
      pk[0] = __builtin_amdgcn_perm(fbits(e1), fbits(e0), 0x07060302);
      pk[1] = __builtin_amdgcn_perm(fbits(e3), fbits(e2), 0x07060302);
      *(u32x2*)&sP[(w * 16 + l16) * PST + n * 16 + quad * 4] = pk;
    }
    // sP rows are per-wave -> no barrier before PV

    // ctx^T += V^T . P^T : D[d=quad*4+j][q=l16]
    short8 pf0 = *(const short8*)&sP[(w * 16 + l16) * PST + quad * 8];
    short8 pf1 = *(const short8*)&sP[(w * 16 + l16) * PST + 32 + quad * 8];
    for (int n2 = 0; n2 < 4; ++n2) {
      short8 vf0 = *(const short8*)&sVT[(n2 * 16 + l16) * PST + quad * 8];
      short8 vf1 = *(const short8*)&sVT[(n2 * 16 + l16) * PST + 32 + quad * 8];
      accpv[n2] = __builtin_amdgcn_mfma_f32_16x16x32_bf16(vf0, pf0, accpv[n2], 0, 0, 0);
      accpv[n2] = __builtin_amdgcn_mfma_f32_16x16x32_bf16(vf1, pf1, accpv[n2], 0, 0, 0);
    }
  }

  // den lives per-lane for query l16; reduce across the 4 quad replicas
  den += __shfl_xor(den, 16, 64);
  den += __shfl_xor(den, 32, 64);
  float inv = 1.f / (den + 1e-8f);

  // output: thread holds ctx[q = w*16+l16][d = n2*16 + quad*4 + j] -> float4
  {
    int q = qt * 64 + w * 16 + l16;
    float* dst = ctx + (size_t)(b * SEQ + q) * D_MODEL + h * D_KH;
    for (int n2 = 0; n2 < 4; ++n2) {
      f32x4 o = accpv[n2];
      float4 v = make_float4(o[0] * inv, o[1] * inv, o[2] * inv, o[3] * inv);
      *(float4*)(dst + n2 * 16 + quad * 4) = v;
    }
  }
}

// ---------------------------------------------------------------- launch
extern "C" void kernel_launch(void* const* d_in, const int* in_sizes, int n_in,
                              void* d_out, int out_size, void* d_ws, size_t ws_size,
                              hipStream_t stream) {
  const float* Q      = (const float*)d_in[0];
  const int*   length = (const int*)d_in[1];
  const float* Wq     = (const float*)d_in[2];
  const float* bq     = (const float*)d_in[3];
  const float* Wk     = (const float*)d_in[4];
  const float* bk     = (const float*)d_in[5];
  const float* Wv     = (const float*)d_in[6];
  const float* bv     = (const float*)d_in[7];

  float* out_ctx = (float*)d_out;                         // [8192,1024]
  float* out_qa  = out_ctx + (size_t)M_TOTAL * D_MODEL;   // [8192,1024]

  char* ws = (char*)d_ws;
  unsigned short* Qbf = (unsigned short*)ws;                              // 16 MB
  unsigned short* WT  = (unsigned short*)(ws + (size_t)16 * 1024 * 1024); //  6 MB
  unsigned short* Kbf = (unsigned short*)(ws + (size_t)22 * 1024 * 1024); // 16 MB
  unsigned short* Vt  = (unsigned short*)(ws + (size_t)38 * 1024 * 1024); // 16 MB

  hipLaunchKernelGGL(cvt_q, dim3((M_TOTAL * D_MODEL) / (256 * 4)), dim3(256), 0, stream,
                     Q, Qbf);
  hipLaunchKernelGGL(cvt_wt, dim3(32, 32, 3), dim3(256), 0, stream, Wq, Wk, Wv, WT);
  hipLaunchKernelGGL(gemm_qkv, dim3(D_MODEL / BN, M_TOTAL / BM, 3), dim3(256), 0, stream,
                     Qbf, WT, bq, bk, bv, out_qa, Kbf, Vt);
  hipLaunchKernelGGL(attn, dim3(SEQ / 64, BATCH * N_HEADS), dim3(256), 0, stream,
                     out_qa, Kbf, Vt, length, out_ctx);
}